// Round 4
// baseline (238.251 us; speedup 1.0000x reference)
//
#include <hip/hip_runtime.h>
#include <math.h>

#define N_NODES  100000
#define N_HEDGES 100000
#define N_INC    1000000
#define IN_DIM   128

#define SHIFT    7
#define BMASK    127
#define NBKT     782        // ceil(100000/128); 782*128 = 100096
#define PH1_ITEMS 4096
#define NBLK     245        // ceil(1e6/4096)

typedef unsigned int u32;

// ---------------------------------------------------------------------------
// W12 = W1 @ W2 (128x3), cvec = b1 @ W2 (3)
__global__ void w12_kernel(const float* __restrict__ W1, const float* __restrict__ b1,
                           const float* __restrict__ W2, float* __restrict__ W12,
                           float* __restrict__ cvec) {
    int k = threadIdx.x;
    if (k < 128) {
        float a0 = 0.f, a1 = 0.f, a2 = 0.f;
        for (int m = 0; m < 64; ++m) {
            float w = W1[k * 64 + m];
            a0 += w * W2[m * 3 + 0];
            a1 += w * W2[m * 3 + 1];
            a2 += w * W2[m * 3 + 2];
        }
        W12[k * 3 + 0] = a0;
        W12[k * 3 + 1] = a1;
        W12[k * 3 + 2] = a2;
    }
    if (k < 3) {
        float c = 0.f;
        for (int m = 0; m < 64; ++m) c += b1[m] * W2[m * 3 + k];
        cvec[k] = c;
    }
}

// ---------------------------------------------------------------------------
// Z[n][0..2] = X[n][:] @ W12 — one wave per node, float2 per lane
__global__ void gemm_z_kernel(const float* __restrict__ X, const float* __restrict__ W12,
                              float* __restrict__ Z, int n_nodes) {
    __shared__ float w[IN_DIM * 3];
    int tid = threadIdx.x;
    for (int i = tid; i < IN_DIM * 3; i += blockDim.x) w[i] = W12[i];
    __syncthreads();

    int wave = tid >> 6;
    int lane = tid & 63;
    int node = blockIdx.x * 4 + wave;
    if (node >= n_nodes) return;

    float2 x2 = ((const float2*)(X + (size_t)node * IN_DIM))[lane];
    int k0 = 2 * lane, k1 = 2 * lane + 1;
    float a0 = x2.x * w[k0 * 3 + 0] + x2.y * w[k1 * 3 + 0];
    float a1 = x2.x * w[k0 * 3 + 1] + x2.y * w[k1 * 3 + 1];
    float a2 = x2.x * w[k0 * 3 + 2] + x2.y * w[k1 * 3 + 2];

    #pragma unroll
    for (int off = 32; off > 0; off >>= 1) {
        a0 += __shfl_xor(a0, off);
        a1 += __shfl_xor(a1, off);
        a2 += __shfl_xor(a2, off);
    }
    if (lane == 0) {
        Z[(size_t)node * 4 + 0] = a0;
        Z[(size_t)node * 4 + 1] = a1;
        Z[(size_t)node * 4 + 2] = a2;
        Z[(size_t)node * 4 + 3] = 0.f;
    }
}

// ---------------------------------------------------------------------------
// 1a: per-block LDS histograms over 782 coarse buckets (both directions);
//     tmp = rank_n | (rank_h << 12)  (ranks < 4096).
__global__ void bin_count_kernel(const int* __restrict__ ei0, const int* __restrict__ ei1,
                                 u32* __restrict__ tmp, int* __restrict__ histmat) {
    __shared__ int hn[NBKT], hh[NBKT];
    int blk = blockIdx.x, t = threadIdx.x;
    for (int i = t; i < NBKT; i += 256) { hn[i] = 0; hh[i] = 0; }
    __syncthreads();
    int base = blk * PH1_ITEMS;
    #pragma unroll
    for (int k = 0; k < 16; ++k) {
        int i = base + t + k * 256;
        if (i < N_INC) {
            int n = ei0[i], h = ei1[i];
            int rn = atomicAdd(&hn[n >> SHIFT], 1);
            int rh = atomicAdd(&hh[h >> SHIFT], 1);
            tmp[i] = (u32)rn | ((u32)rh << 12);
        }
    }
    __syncthreads();
    for (int i = t; i < NBKT; i += 256) {
        histmat[blk * NBKT + i]          = hn[i];
        histmat[(NBLK + blk) * NBKT + i] = hh[i];
    }
}

// 1b-A: per-column wave scan. One wave per (dir,bucket) column; exclusive
// prefix over the 245 block entries written in place; column total -> tot.
__global__ void scanA_kernel(int* __restrict__ histmat, int* __restrict__ tot) {
    int wid = (blockIdx.x * blockDim.x + threadIdx.x) >> 6;
    int lane = threadIdx.x & 63;
    if (wid >= 2 * NBKT) return;
    int dir = wid / NBKT, b = wid % NBKT;
    int* col = histmat + (size_t)dir * NBLK * NBKT + b;
    int carry = 0;
    #pragma unroll
    for (int r = 0; r < 4; ++r) {
        int idx = r * 64 + lane;
        int v = (idx < NBLK) ? col[(size_t)idx * NBKT] : 0;
        int s = v;
        #pragma unroll
        for (int d = 1; d < 64; d <<= 1) {
            int u = __shfl_up(s, d);
            if (lane >= d) s += u;
        }
        int total = __shfl(s, 63);
        if (idx < NBLK) col[(size_t)idx * NBKT] = s - v + carry;
        carry += total;
    }
    if (lane == 63) tot[wid] = carry;
}

// 1b-B: scan the 782 column totals per dir -> bucket bases boff.
__global__ void scanB_kernel(const int* __restrict__ tot,
                             int* __restrict__ boff_n, int* __restrict__ boff_h) {
    __shared__ int s[1024];
    int t = threadIdx.x;
    for (int dir = 0; dir < 2; ++dir) {
        int* boff = dir ? boff_h : boff_n;
        int v = (t < NBKT) ? tot[dir * NBKT + t] : 0;
        s[t] = v;
        __syncthreads();
        for (int d = 1; d < 1024; d <<= 1) {
            int u = (t >= d) ? s[t - d] : 0;
            __syncthreads();
            s[t] += u;
            __syncthreads();
        }
        if (t < NBKT) boff[t] = s[t] - v;   // exclusive
        if (t == 0) boff[NBKT] = N_INC;
        __syncthreads();
    }
}

// 1c: place packed payload (dest_lo<<17 | src) into bucket-grouped order.
__global__ void place_kernel(const int* __restrict__ ei0, const int* __restrict__ ei1,
                             const u32* __restrict__ tmp, const int* __restrict__ histmat,
                             const int* __restrict__ boff_n, const int* __restrict__ boff_h,
                             u32* __restrict__ payload_n, u32* __restrict__ payload_h) {
    int blk = blockIdx.x, t = threadIdx.x;
    int base = blk * PH1_ITEMS;
    #pragma unroll
    for (int k = 0; k < 16; ++k) {
        int i = base + t + k * 256;
        if (i < N_INC) {
            int n = ei0[i], h = ei1[i];
            u32 tv = tmp[i];
            int rn = (int)(tv & 0xFFF), rh = (int)(tv >> 12);
            int bn = n >> SHIFT, bh = h >> SHIFT;
            int pn = histmat[blk * NBKT + bn] + boff_n[bn] + rn;
            int ph = histmat[(size_t)(NBLK + blk) * NBKT + bh] + boff_h[bh] + rh;
            payload_n[pn] = ((u32)(n & BMASK) << 17) | (u32)h;   // dest=node, src=hedge
            payload_h[ph] = ((u32)(h & BMASK) << 17) | (u32)n;   // dest=hedge, src=node
        }
    }
}

// ---------------------------------------------------------------------------
// seg-mean via per-bucket LDS accumulation: one block per coarse bucket.
// dst[dest] = mean over bucket items of src[src_id] (+ addv); count in .w.
__global__ void seg_mean_kernel(const float* __restrict__ src, float* __restrict__ dst,
                                const u32* __restrict__ payload, const int* __restrict__ boff,
                                const float* __restrict__ addv, int nrows) {
    __shared__ float acc[128][4];
    int b = blockIdx.x, t = threadIdx.x;
    for (int i = t; i < 512; i += 256) ((float*)acc)[i] = 0.f;
    __syncthreads();
    int base = boff[b], end = boff[b + 1];
    for (int j = base + t; j < end; j += 256) {
        u32 p = payload[j];
        int d = (int)(p >> 17);
        float4 v = ((const float4*)src)[p & 0x1FFFF];
        atomicAdd(&acc[d][0], v.x);
        atomicAdd(&acc[d][1], v.y);
        atomicAdd(&acc[d][2], v.z);
        atomicAdd(&acc[d][3], 1.0f);
    }
    __syncthreads();
    if (t < 128) {
        int dest = (b << SHIFT) + t;
        if (dest < nrows) {
            float c = acc[t][3];
            float inv = c > 0.f ? 1.0f / c : 0.f;
            float b0 = 0.f, b1 = 0.f, b2 = 0.f;
            if (addv) { b0 = addv[0]; b1 = addv[1]; b2 = addv[2]; }
            ((float4*)dst)[dest] = make_float4(acc[t][0] * inv + b0,
                                               acc[t][1] * inv + b1,
                                               acc[t][2] * inv + b2, 0.f);
        }
    }
}

// same accumulation (hedge dir), fused with sigmoid/normalize/gumbel/argmax
__global__ void hedge_final_kernel(const float* __restrict__ H2,
                                   const u32* __restrict__ payload_h, const int* __restrict__ boff_h,
                                   const float* __restrict__ gu, float* __restrict__ hard0,
                                   float* __restrict__ hard2) {
    __shared__ float acc[128][4];
    int b = blockIdx.x, t = threadIdx.x;
    for (int i = t; i < 512; i += 256) ((float*)acc)[i] = 0.f;
    __syncthreads();
    int base = boff_h[b], end = boff_h[b + 1];
    for (int j = base + t; j < end; j += 256) {
        u32 p = payload_h[j];
        int d = (int)(p >> 17);
        float4 v = ((const float4*)H2)[p & 0x1FFFF];
        atomicAdd(&acc[d][0], v.x);
        atomicAdd(&acc[d][1], v.y);
        atomicAdd(&acc[d][2], v.z);
        atomicAdd(&acc[d][3], 1.0f);
    }
    __syncthreads();
    if (t < 128) {
        int h = (b << SHIFT) + t;
        if (h < N_HEDGES) {
            float c = acc[t][3];
            float binv = c > 0.f ? 1.0f / c : 0.f;
            float s0 = acc[t][0] * binv, s1 = acc[t][1] * binv, s2 = acc[t][2] * binv;
            float x0 = 1.0f / (1.0f + expf(-s0));
            float x1 = 1.0f / (1.0f + expf(-s1));
            float x2 = 1.0f / (1.0f + expf(-s2));
            float rs = x0 + x1 + x2;
            float rinv = rs != 0.f ? 1.0f / rs : 0.f;
            x0 *= rinv; x1 *= rinv; x2 *= rinv;
            const float EPS = 1e-10f;
            float g0 = -logf(-logf(gu[(size_t)h * 3 + 0] + EPS) + EPS);
            float g1 = -logf(-logf(gu[(size_t)h * 3 + 1] + EPS) + EPS);
            float g2 = -logf(-logf(gu[(size_t)h * 3 + 2] + EPS) + EPS);
            // argmax(softmax(x)) == argmax(x); first-max wins like jnp.argmax
            float v0 = x0 + g0, v1 = x1 + g1, v2 = x2 + g2;
            int am = 0; float vm = v0;
            if (v1 > vm) { am = 1; vm = v1; }
            if (v2 > vm) { am = 2; vm = v2; }
            hard0[h] = (am == 0) ? 1.f : 0.f;
            hard2[h] = (am == 2) ? 1.f : 0.f;
        }
    }
}

// per-incidence: sample + masked edge_index
__global__ void edge_final_kernel(const float* __restrict__ hard0, const float* __restrict__ hard2,
                                  const float* __restrict__ ov,
                                  const int* __restrict__ ei0, const int* __restrict__ ei1,
                                  float* __restrict__ out, int n) {
    int i = blockIdx.x * blockDim.x + threadIdx.x;
    if (i >= n) return;
    int nn = ei0[i], hh = ei1[i];
    float r = hard0[hh];
    float m = hard2[hh] * (ov[nn] < 0.5f ? 1.f : 0.f);
    float s = fmaxf(r, m);
    out[i] = s;
    bool keep = s > 0.f;
    out[(size_t)N_INC + i]     = keep ? (float)nn : -1.f;
    out[(size_t)2 * N_INC + i] = keep ? (float)hh : -1.f;
}

// ---------------------------------------------------------------------------
extern "C" void kernel_launch(void* const* d_in, const int* in_sizes, int n_in,
                              void* d_out, int out_size, void* d_ws, size_t ws_size,
                              hipStream_t stream) {
    const float* X  = (const float*)d_in[0];
    const float* W1 = (const float*)d_in[1];
    const float* b1 = (const float*)d_in[2];
    const float* W2 = (const float*)d_in[3];
    const float* b2 = (const float*)d_in[4];
    const float* ov = (const float*)d_in[5];
    const float* gu = (const float*)d_in[6];
    const int*   ei = (const int*)d_in[7];
    const int* ei0 = ei;            // nodes
    const int* ei1 = ei + N_INC;    // hedges

    // ---- workspace layout (section starts 16B aligned) ----
    int* ip = (int*)d_ws;
    u32* payload_n = (u32*)ip;                    // 1M  (alive through finals)
    u32* payload_h = payload_n + N_INC;           // 1M
    u32* tmp       = payload_h + N_INC;           // 1M  (dead after place)
    int* histmat   = (int*)(tmp + N_INC);         // 2*NBLK*NBKT = 383180 -> 383200
    int* tot       = histmat + 383200;            // 2*NBKT = 1564 -> 1568
    int* boff_n    = tot + 1568;                  // 784
    int* boff_h    = boff_n + 784;                // 784
    float* W12     = (float*)(boff_h + 784);      // 384
    float* cvec    = W12 + 384;                   // 4
    float* Z       = cvec + 12;                   // 4*N_NODES  (16B aligned: 384+4+12=400)
    float* XeA     = Z    + 4 * N_NODES;          // 4*N_HEDGES
    float* XnA     = XeA  + 4 * N_HEDGES;         // 4*N_NODES
    float* XeB     = XnA  + 4 * N_NODES;          // 4*N_HEDGES
    float* XnB     = XeB  + 4 * N_HEDGES;         // 4*N_NODES (= H2)
    // hard0/2 alias tmp (tmp dead after place_kernel)
    float* hard0   = (float*)tmp;                 // 100k
    float* hard2   = hard0 + N_HEDGES;            // 100k

    const int TB = 256;
    int gInc = (N_INC + TB - 1) / TB;

    w12_kernel<<<1, 128, 0, stream>>>(W1, b1, W2, W12, cvec);
    gemm_z_kernel<<<(N_NODES + 3) / 4, 256, 0, stream>>>(X, W12, Z, N_NODES);

    // bucket-grouped payload build (atomic-free, LDS ranks + wave scans)
    bin_count_kernel<<<NBLK, 256, 0, stream>>>(ei0, ei1, tmp, histmat);
    scanA_kernel<<<(2 * NBKT + 3) / 4, 256, 0, stream>>>(histmat, tot);
    scanB_kernel<<<1, 1024, 0, stream>>>(tot, boff_n, boff_h);
    place_kernel<<<NBLK, 256, 0, stream>>>(ei0, ei1, tmp, histmat, boff_n, boff_h,
                                           payload_n, payload_h);

    // layer 1: Xe = mean_hedge(Z); Xn = mean_node(Xe) + cvec
    seg_mean_kernel<<<NBKT, 256, 0, stream>>>(Z,   XeA, payload_h, boff_h, nullptr, N_HEDGES);
    seg_mean_kernel<<<NBKT, 256, 0, stream>>>(XeA, XnA, payload_n, boff_n, cvec,    N_NODES);
    // layer 2: H2 = mean_node(mean_hedge(XnA)) + b2
    seg_mean_kernel<<<NBKT, 256, 0, stream>>>(XnA, XeB, payload_h, boff_h, nullptr, N_HEDGES);
    seg_mean_kernel<<<NBKT, 256, 0, stream>>>(XeB, XnB, payload_n, boff_n, b2,      N_NODES);

    // scatter-mean of H2 into hedges fused with sigmoid/normalize/gumbel/argmax
    hedge_final_kernel<<<NBKT, 256, 0, stream>>>(XnB, payload_h, boff_h, gu, hard0, hard2);

    edge_final_kernel<<<gInc, TB, 0, stream>>>(hard0, hard2, ov, ei0, ei1,
                                               (float*)d_out, N_INC);
}

// Round 5
// 167.471 us; speedup vs baseline: 1.4226x; 1.4226x over previous
//
#include <hip/hip_runtime.h>
#include <math.h>

#define N_NODES  100000
#define N_HEDGES 100000
#define N_INC    1000000
#define IN_DIM   128

#define SHIFT    7
#define BMASK    127
#define NBKT     782        // ceil(100000/128); 782*128 = 100096
#define PH1_ITEMS 4096
#define NBLK     245        // ceil(1e6/4096)

typedef unsigned int u32;

// ---------------------------------------------------------------------------
// W12 = W1 @ W2 (128x3), cvec = b1 @ W2 (3)
__global__ void w12_kernel(const float* __restrict__ W1, const float* __restrict__ b1,
                           const float* __restrict__ W2, float* __restrict__ W12,
                           float* __restrict__ cvec) {
    int k = threadIdx.x;
    if (k < 128) {
        float a0 = 0.f, a1 = 0.f, a2 = 0.f;
        for (int m = 0; m < 64; ++m) {
            float w = W1[k * 64 + m];
            a0 += w * W2[m * 3 + 0];
            a1 += w * W2[m * 3 + 1];
            a2 += w * W2[m * 3 + 2];
        }
        W12[k * 3 + 0] = a0;
        W12[k * 3 + 1] = a1;
        W12[k * 3 + 2] = a2;
    }
    if (k < 3) {
        float c = 0.f;
        for (int m = 0; m < 64; ++m) c += b1[m] * W2[m * 3 + k];
        cvec[k] = c;
    }
}

// ---------------------------------------------------------------------------
// Z[n][0..2] = X[n][:] @ W12 — one wave per node, float2 per lane
__global__ void gemm_z_kernel(const float* __restrict__ X, const float* __restrict__ W12,
                              float* __restrict__ Z, int n_nodes) {
    __shared__ float w[IN_DIM * 3];
    int tid = threadIdx.x;
    for (int i = tid; i < IN_DIM * 3; i += blockDim.x) w[i] = W12[i];
    __syncthreads();

    int wave = tid >> 6;
    int lane = tid & 63;
    int node = blockIdx.x * 4 + wave;
    if (node >= n_nodes) return;

    float2 x2 = ((const float2*)(X + (size_t)node * IN_DIM))[lane];
    int k0 = 2 * lane, k1 = 2 * lane + 1;
    float a0 = x2.x * w[k0 * 3 + 0] + x2.y * w[k1 * 3 + 0];
    float a1 = x2.x * w[k0 * 3 + 1] + x2.y * w[k1 * 3 + 1];
    float a2 = x2.x * w[k0 * 3 + 2] + x2.y * w[k1 * 3 + 2];

    #pragma unroll
    for (int off = 32; off > 0; off >>= 1) {
        a0 += __shfl_xor(a0, off);
        a1 += __shfl_xor(a1, off);
        a2 += __shfl_xor(a2, off);
    }
    if (lane == 0) {
        Z[(size_t)node * 4 + 0] = a0;
        Z[(size_t)node * 4 + 1] = a1;
        Z[(size_t)node * 4 + 2] = a2;
        Z[(size_t)node * 4 + 3] = 0.f;
    }
}

// ---------------------------------------------------------------------------
// 1a: per-block LDS histograms over 782 coarse buckets (both directions);
//     tmp = rank_n | (rank_h << 12)  (ranks < 4096).
__global__ void bin_count_kernel(const int* __restrict__ ei0, const int* __restrict__ ei1,
                                 u32* __restrict__ tmp, int* __restrict__ histmat) {
    __shared__ int hn[NBKT], hh[NBKT];
    int blk = blockIdx.x, t = threadIdx.x;
    for (int i = t; i < NBKT; i += 256) { hn[i] = 0; hh[i] = 0; }
    __syncthreads();
    int base = blk * PH1_ITEMS;
    #pragma unroll
    for (int k = 0; k < 16; ++k) {
        int i = base + t + k * 256;
        if (i < N_INC) {
            int n = ei0[i], h = ei1[i];
            int rn = atomicAdd(&hn[n >> SHIFT], 1);
            int rh = atomicAdd(&hh[h >> SHIFT], 1);
            tmp[i] = (u32)rn | ((u32)rh << 12);
        }
    }
    __syncthreads();
    for (int i = t; i < NBKT; i += 256) {
        histmat[blk * NBKT + i]          = hn[i];
        histmat[(NBLK + blk) * NBKT + i] = hh[i];
    }
}

// 1b-A: per-column wave scan. One wave per (dir,bucket) column; exclusive
// prefix over the 245 block entries written in place; column total -> tot.
__global__ void scanA_kernel(int* __restrict__ histmat, int* __restrict__ tot) {
    int wid = (blockIdx.x * blockDim.x + threadIdx.x) >> 6;
    int lane = threadIdx.x & 63;
    if (wid >= 2 * NBKT) return;
    int dir = wid / NBKT, b = wid % NBKT;
    int* col = histmat + (size_t)dir * NBLK * NBKT + b;
    int carry = 0;
    #pragma unroll
    for (int r = 0; r < 4; ++r) {
        int idx = r * 64 + lane;
        int v = (idx < NBLK) ? col[(size_t)idx * NBKT] : 0;
        int s = v;
        #pragma unroll
        for (int d = 1; d < 64; d <<= 1) {
            int u = __shfl_up(s, d);
            if (lane >= d) s += u;
        }
        int total = __shfl(s, 63);
        if (idx < NBLK) col[(size_t)idx * NBKT] = s - v + carry;
        carry += total;
    }
    if (lane == 63) tot[wid] = carry;
}

// 1b-B: scan the 782 column totals per dir -> bucket bases boff; off[N] = N_INC.
__global__ void scanB_kernel(const int* __restrict__ tot,
                             int* __restrict__ boff_n, int* __restrict__ boff_h,
                             int* __restrict__ off_n, int* __restrict__ off_h) {
    __shared__ int s[1024];
    int t = threadIdx.x;
    for (int dir = 0; dir < 2; ++dir) {
        int* boff = dir ? boff_h : boff_n;
        int* off  = dir ? off_h  : off_n;
        int v = (t < NBKT) ? tot[dir * NBKT + t] : 0;
        s[t] = v;
        __syncthreads();
        for (int d = 1; d < 1024; d <<= 1) {
            int u = (t >= d) ? s[t - d] : 0;
            __syncthreads();
            s[t] += u;
            __syncthreads();
        }
        if (t < NBKT) boff[t] = s[t] - v;   // exclusive
        if (t == 0) { boff[NBKT] = N_INC; off[N_NODES] = N_INC; }
        __syncthreads();
    }
}

// 1c: place packed payload (dest_lo<<17 | src) into bucket-grouped order.
__global__ void place_kernel(const int* __restrict__ ei0, const int* __restrict__ ei1,
                             const u32* __restrict__ tmp, const int* __restrict__ histmat,
                             const int* __restrict__ boff_n, const int* __restrict__ boff_h,
                             u32* __restrict__ payload_n, u32* __restrict__ payload_h) {
    int blk = blockIdx.x, t = threadIdx.x;
    int base = blk * PH1_ITEMS;
    #pragma unroll
    for (int k = 0; k < 16; ++k) {
        int i = base + t + k * 256;
        if (i < N_INC) {
            int n = ei0[i], h = ei1[i];
            u32 tv = tmp[i];
            int rn = (int)(tv & 0xFFF), rh = (int)(tv >> 12);
            int bn = n >> SHIFT, bh = h >> SHIFT;
            int pn = histmat[blk * NBKT + bn] + boff_n[bn] + rn;
            int ph = histmat[(size_t)(NBLK + blk) * NBKT + bh] + boff_h[bh] + rh;
            payload_n[pn] = ((u32)(n & BMASK) << 17) | (u32)h;   // dest=node, src=hedge
            payload_h[ph] = ((u32)(h & BMASK) << 17) | (u32)n;   // dest=hedge, src=node
        }
    }
}

// 2: per (bucket, dir): 128-bin LDS count + scan -> CSR off + dest-grouped slots.
__global__ void phase2_kernel(const u32* __restrict__ payload_n, const u32* __restrict__ payload_h,
                              const int* __restrict__ boff_n, const int* __restrict__ boff_h,
                              int* __restrict__ off_n, int* __restrict__ off_h,
                              int* __restrict__ slot_n, int* __restrict__ slot_h) {
    __shared__ int cnt[128], pre[128];
    int b = blockIdx.x, t = threadIdx.x;
    const u32* payload = blockIdx.y ? payload_h : payload_n;
    const int* boff    = blockIdx.y ? boff_h    : boff_n;
    int* off  = blockIdx.y ? off_h  : off_n;
    int* slot = blockIdx.y ? slot_h : slot_n;

    int base = boff[b], end = boff[b + 1];
    if (t < 128) cnt[t] = 0;
    __syncthreads();
    for (int j = base + t; j < end; j += 256) atomicAdd(&cnt[payload[j] >> 17], 1);
    __syncthreads();
    if (t < 128) pre[t] = cnt[t];
    __syncthreads();
    for (int d = 1; d < 128; d <<= 1) {
        int v = (t >= d && t < 128) ? pre[t - d] : 0;
        __syncthreads();
        if (t < 128) pre[t] += v;
        __syncthreads();
    }
    if (t < 128) {
        int e = pre[t] - cnt[t];           // exclusive
        int dest = (b << SHIFT) + t;
        if (dest < N_NODES) off[dest] = base + e;
        cnt[t] = e;                        // becomes cursor
    }
    __syncthreads();
    for (int j = base + t; j < end; j += 256) {
        u32 p = payload[j];
        int r = atomicAdd(&cnt[p >> 17], 1);
        slot[base + r] = (int)(p & 0x1FFFF);
    }
}

// ---------------------------------------------------------------------------
// dst[r] = (1/deg) * sum_{j in seg(r)} src[slot[j]]  (+ addv), rows = 4 floats
__global__ void gather_kernel(const float* __restrict__ src, float* __restrict__ dst,
                              const int* __restrict__ off, const int* __restrict__ slot,
                              const float* __restrict__ addv, int nrows) {
    int r = blockIdx.x * blockDim.x + threadIdx.x;
    if (r >= nrows) return;
    int s = off[r], e = off[r + 1];
    float a0 = 0.f, a1 = 0.f, a2 = 0.f;
    for (int j = s; j < e; ++j) {
        float4 v = ((const float4*)src)[slot[j]];
        a0 += v.x; a1 += v.y; a2 += v.z;
    }
    float inv = (e > s) ? 1.0f / (float)(e - s) : 0.f;
    float b0 = 0.f, b1 = 0.f, b2 = 0.f;
    if (addv) { b0 = addv[0]; b1 = addv[1]; b2 = addv[2]; }
    ((float4*)dst)[r] = make_float4(a0 * inv + b0, a1 * inv + b1, a2 * inv + b2, 0.f);
}

// per-hedge: gather-mean of H2 -> sigmoid -> rowsum-normalize -> +gumbel -> argmax
__global__ void hedge_final_kernel(const float* __restrict__ H2,
                                   const int* __restrict__ off_h, const int* __restrict__ slot_h,
                                   const float* __restrict__ gu, float* __restrict__ hard0,
                                   float* __restrict__ hard2, int n) {
    int h = blockIdx.x * blockDim.x + threadIdx.x;
    if (h >= n) return;
    int s = off_h[h], e = off_h[h + 1];
    float a0 = 0.f, a1 = 0.f, a2 = 0.f;
    for (int j = s; j < e; ++j) {
        float4 v = ((const float4*)H2)[slot_h[j]];
        a0 += v.x; a1 += v.y; a2 += v.z;
    }
    float binv = (e > s) ? 1.0f / (float)(e - s) : 0.f;
    float s0 = a0 * binv, s1 = a1 * binv, s2 = a2 * binv;
    float x0 = 1.0f / (1.0f + expf(-s0));
    float x1 = 1.0f / (1.0f + expf(-s1));
    float x2 = 1.0f / (1.0f + expf(-s2));
    float rs = x0 + x1 + x2;
    float rinv = rs != 0.f ? 1.0f / rs : 0.f;
    x0 *= rinv; x1 *= rinv; x2 *= rinv;
    const float EPS = 1e-10f;
    float g0 = -logf(-logf(gu[(size_t)h * 3 + 0] + EPS) + EPS);
    float g1 = -logf(-logf(gu[(size_t)h * 3 + 1] + EPS) + EPS);
    float g2 = -logf(-logf(gu[(size_t)h * 3 + 2] + EPS) + EPS);
    // argmax(softmax(x)) == argmax(x); first-max wins like jnp.argmax
    float v0 = x0 + g0, v1 = x1 + g1, v2 = x2 + g2;
    int am = 0; float vm = v0;
    if (v1 > vm) { am = 1; vm = v1; }
    if (v2 > vm) { am = 2; vm = v2; }
    hard0[h] = (am == 0) ? 1.f : 0.f;
    hard2[h] = (am == 2) ? 1.f : 0.f;
}

// per-incidence: sample + masked edge_index
__global__ void edge_final_kernel(const float* __restrict__ hard0, const float* __restrict__ hard2,
                                  const float* __restrict__ ov,
                                  const int* __restrict__ ei0, const int* __restrict__ ei1,
                                  float* __restrict__ out, int n) {
    int i = blockIdx.x * blockDim.x + threadIdx.x;
    if (i >= n) return;
    int nn = ei0[i], hh = ei1[i];
    float r = hard0[hh];
    float m = hard2[hh] * (ov[nn] < 0.5f ? 1.f : 0.f);
    float s = fmaxf(r, m);
    out[i] = s;
    bool keep = s > 0.f;
    out[(size_t)N_INC + i]     = keep ? (float)nn : -1.f;
    out[(size_t)2 * N_INC + i] = keep ? (float)hh : -1.f;
}

// ---------------------------------------------------------------------------
extern "C" void kernel_launch(void* const* d_in, const int* in_sizes, int n_in,
                              void* d_out, int out_size, void* d_ws, size_t ws_size,
                              hipStream_t stream) {
    const float* X  = (const float*)d_in[0];
    const float* W1 = (const float*)d_in[1];
    const float* b1 = (const float*)d_in[2];
    const float* W2 = (const float*)d_in[3];
    const float* b2 = (const float*)d_in[4];
    const float* ov = (const float*)d_in[5];
    const float* gu = (const float*)d_in[6];
    const int*   ei = (const int*)d_in[7];
    const int* ei0 = ei;            // nodes
    const int* ei1 = ei + N_INC;    // hedges

    // ---- workspace layout (no aliasing; all section starts 16B aligned) ----
    int* ip = (int*)d_ws;
    u32* tmp       = (u32*)ip;                    // 1M
    u32* payload_n = tmp + N_INC;                 // 1M
    u32* payload_h = payload_n + N_INC;           // 1M
    int* slot_n    = (int*)(payload_h + N_INC);   // 1M
    int* slot_h    = slot_n + N_INC;              // 1M
    int* off_n     = slot_h + N_INC;              // 100004
    int* off_h     = off_n + 100004;              // 100004
    int* histmat   = off_h + 100004;              // 2*NBLK*NBKT = 383180 -> 383200
    int* tot       = histmat + 383200;            // 2*NBKT = 1564 -> 1568
    int* boff_n    = tot + 1568;                  // 784
    int* boff_h    = boff_n + 784;                // 784
    float* W12     = (float*)(boff_h + 784);      // 384
    float* cvec    = W12 + 384;                   // 4 (+12 pad)
    float* Z       = cvec + 12;                   // 4*N_NODES
    float* XeA     = Z    + 4 * N_NODES;          // 4*N_HEDGES
    float* XnA     = XeA  + 4 * N_HEDGES;         // 4*N_NODES
    float* XeB     = XnA  + 4 * N_NODES;          // 4*N_HEDGES
    float* XnB     = XeB  + 4 * N_HEDGES;         // 4*N_NODES (= H2)
    float* hard0   = XnB  + 4 * N_NODES;          // 100k
    float* hard2   = hard0 + N_HEDGES;            // 100k

    const int TB = 256;
    int gInc = (N_INC + TB - 1) / TB;
    int gHed = (N_HEDGES + TB - 1) / TB;

    w12_kernel<<<1, 128, 0, stream>>>(W1, b1, W2, W12, cvec);
    gemm_z_kernel<<<(N_NODES + 3) / 4, 256, 0, stream>>>(X, W12, Z, N_NODES);

    // CSR build: LDS histograms + parallel scans + bucket place + bucket sort
    bin_count_kernel<<<NBLK, 256, 0, stream>>>(ei0, ei1, tmp, histmat);
    scanA_kernel<<<(2 * NBKT + 3) / 4, 256, 0, stream>>>(histmat, tot);
    scanB_kernel<<<1, 1024, 0, stream>>>(tot, boff_n, boff_h, off_n, off_h);
    place_kernel<<<NBLK, 256, 0, stream>>>(ei0, ei1, tmp, histmat, boff_n, boff_h,
                                           payload_n, payload_h);
    phase2_kernel<<<dim3(NBKT, 2), 256, 0, stream>>>(payload_n, payload_h, boff_n, boff_h,
                                                     off_n, off_h, slot_n, slot_h);

    // layer 1: Xe = mean_hedge(Z); Xn = mean_node(Xe) + cvec
    gather_kernel<<<gHed, TB, 0, stream>>>(Z,   XeA, off_h, slot_h, nullptr, N_HEDGES);
    gather_kernel<<<gHed, TB, 0, stream>>>(XeA, XnA, off_n, slot_n, cvec,    N_NODES);
    // layer 2: H2 = mean_node(mean_hedge(XnA)) + b2
    gather_kernel<<<gHed, TB, 0, stream>>>(XnA, XeB, off_h, slot_h, nullptr, N_HEDGES);
    gather_kernel<<<gHed, TB, 0, stream>>>(XeB, XnB, off_n, slot_n, b2,      N_NODES);

    // scatter-mean of H2 into hedges fused with sigmoid/normalize/gumbel/argmax
    hedge_final_kernel<<<gHed, TB, 0, stream>>>(XnB, off_h, slot_h, gu, hard0, hard2, N_HEDGES);

    edge_final_kernel<<<gInc, TB, 0, stream>>>(hard0, hard2, ov, ei0, ei1,
                                               (float*)d_out, N_INC);
}

// Round 6
// 165.230 us; speedup vs baseline: 1.4419x; 1.0136x over previous
//
#include <hip/hip_runtime.h>
#include <math.h>

#define N_NODES  100000
#define N_HEDGES 100000
#define N_INC    1000000
#define IN_DIM   128

#define SHIFT    7
#define BMASK    127
#define NBKT     782        // ceil(100000/128); 782*128 = 100096
#define PH1_ITEMS 4096
#define NBLK     245        // ceil(1e6/4096)

typedef unsigned int u32;

// ---------------------------------------------------------------------------
// 1a: per-block LDS histograms over 782 coarse buckets (both directions).
//     Block 0 additionally computes W12 = W1@W2 and cvec = b1@W2.
__global__ void bin_count_w12_kernel(const int* __restrict__ ei0, const int* __restrict__ ei1,
                                     int* __restrict__ histmat,
                                     const float* __restrict__ W1, const float* __restrict__ b1,
                                     const float* __restrict__ W2, float* __restrict__ W12,
                                     float* __restrict__ cvec) {
    __shared__ int hn[NBKT], hh[NBKT];
    int blk = blockIdx.x, t = threadIdx.x;

    if (blk == 0) {                       // fused tiny W12 pre-pass
        if (t < 128) {
            float a0 = 0.f, a1 = 0.f, a2 = 0.f;
            for (int m = 0; m < 64; ++m) {
                float w = W1[t * 64 + m];
                a0 += w * W2[m * 3 + 0];
                a1 += w * W2[m * 3 + 1];
                a2 += w * W2[m * 3 + 2];
            }
            W12[t * 3 + 0] = a0;
            W12[t * 3 + 1] = a1;
            W12[t * 3 + 2] = a2;
        }
        if (t < 3) {
            float c = 0.f;
            for (int m = 0; m < 64; ++m) c += b1[m] * W2[m * 3 + t];
            cvec[t] = c;
        }
    }

    for (int i = t; i < NBKT; i += 256) { hn[i] = 0; hh[i] = 0; }
    __syncthreads();
    int base4 = blk * (PH1_ITEMS / 4);
    #pragma unroll
    for (int k = 0; k < 4; ++k) {
        int i4 = base4 + k * 256 + t;
        if (i4 * 4 < N_INC) {
            int4 n4 = ((const int4*)ei0)[i4];
            int4 h4 = ((const int4*)ei1)[i4];
            atomicAdd(&hn[n4.x >> SHIFT], 1); atomicAdd(&hh[h4.x >> SHIFT], 1);
            atomicAdd(&hn[n4.y >> SHIFT], 1); atomicAdd(&hh[h4.y >> SHIFT], 1);
            atomicAdd(&hn[n4.z >> SHIFT], 1); atomicAdd(&hh[h4.z >> SHIFT], 1);
            atomicAdd(&hn[n4.w >> SHIFT], 1); atomicAdd(&hh[h4.w >> SHIFT], 1);
        }
    }
    __syncthreads();
    for (int i = t; i < NBKT; i += 256) {
        histmat[blk * NBKT + i]          = hn[i];
        histmat[(NBLK + blk) * NBKT + i] = hh[i];
    }
}

// ---------------------------------------------------------------------------
// Z[n][0..2] = X[n][:] @ W12 — one wave per node, float2 per lane
__global__ void gemm_z_kernel(const float* __restrict__ X, const float* __restrict__ W12,
                              float* __restrict__ Z, int n_nodes) {
    __shared__ float w[IN_DIM * 3];
    int tid = threadIdx.x;
    for (int i = tid; i < IN_DIM * 3; i += blockDim.x) w[i] = W12[i];
    __syncthreads();

    int wave = tid >> 6;
    int lane = tid & 63;
    int node = blockIdx.x * 4 + wave;
    if (node >= n_nodes) return;

    float2 x2 = ((const float2*)(X + (size_t)node * IN_DIM))[lane];
    int k0 = 2 * lane, k1 = 2 * lane + 1;
    float a0 = x2.x * w[k0 * 3 + 0] + x2.y * w[k1 * 3 + 0];
    float a1 = x2.x * w[k0 * 3 + 1] + x2.y * w[k1 * 3 + 1];
    float a2 = x2.x * w[k0 * 3 + 2] + x2.y * w[k1 * 3 + 2];

    #pragma unroll
    for (int off = 32; off > 0; off >>= 1) {
        a0 += __shfl_xor(a0, off);
        a1 += __shfl_xor(a1, off);
        a2 += __shfl_xor(a2, off);
    }
    if (lane == 0) {
        Z[(size_t)node * 4 + 0] = a0;
        Z[(size_t)node * 4 + 1] = a1;
        Z[(size_t)node * 4 + 2] = a2;
        Z[(size_t)node * 4 + 3] = 0.f;
    }
}

// ---------------------------------------------------------------------------
// 1b-A: per-column wave scan (one wave per (dir,bucket) column).
__global__ void scanA_kernel(int* __restrict__ histmat, int* __restrict__ tot) {
    int wid = (blockIdx.x * blockDim.x + threadIdx.x) >> 6;
    int lane = threadIdx.x & 63;
    if (wid >= 2 * NBKT) return;
    int dir = wid / NBKT, b = wid % NBKT;
    int* col = histmat + (size_t)dir * NBLK * NBKT + b;
    int carry = 0;
    #pragma unroll
    for (int r = 0; r < 4; ++r) {
        int idx = r * 64 + lane;
        int v = (idx < NBLK) ? col[(size_t)idx * NBKT] : 0;
        int s = v;
        #pragma unroll
        for (int d = 1; d < 64; d <<= 1) {
            int u = __shfl_up(s, d);
            if (lane >= d) s += u;
        }
        int total = __shfl(s, 63);
        if (idx < NBLK) col[(size_t)idx * NBKT] = s - v + carry;
        carry += total;
    }
    if (lane == 63) tot[wid] = carry;
}

// 1b-B: scan the 782 column totals per dir -> bucket bases boff; off[N] = N_INC.
__global__ void scanB_kernel(const int* __restrict__ tot,
                             int* __restrict__ boff_n, int* __restrict__ boff_h,
                             int* __restrict__ off_n, int* __restrict__ off_h) {
    __shared__ int s[1024];
    int t = threadIdx.x;
    for (int dir = 0; dir < 2; ++dir) {
        int* boff = dir ? boff_h : boff_n;
        int* off  = dir ? off_h  : off_n;
        int v = (t < NBKT) ? tot[dir * NBKT + t] : 0;
        s[t] = v;
        __syncthreads();
        for (int d = 1; d < 1024; d <<= 1) {
            int u = (t >= d) ? s[t - d] : 0;
            __syncthreads();
            s[t] += u;
            __syncthreads();
        }
        if (t < NBKT) boff[t] = s[t] - v;   // exclusive
        if (t == 0) { boff[NBKT] = N_INC; off[N_NODES] = N_INC; }
        __syncthreads();
    }
}

// 1c: place packed payload (dest_lo<<17 | src) into bucket-grouped order.
//     Ranks recomputed locally (any within-bucket bijection is valid).
__global__ void place_kernel(const int* __restrict__ ei0, const int* __restrict__ ei1,
                             const int* __restrict__ histmat,
                             const int* __restrict__ boff_n, const int* __restrict__ boff_h,
                             u32* __restrict__ payload_n, u32* __restrict__ payload_h) {
    __shared__ int hn[NBKT], hh[NBKT];
    int blk = blockIdx.x, t = threadIdx.x;
    for (int i = t; i < NBKT; i += 256) { hn[i] = 0; hh[i] = 0; }
    __syncthreads();
    const int* rown = histmat + (size_t)blk * NBKT;
    const int* rowh = histmat + (size_t)(NBLK + blk) * NBKT;
    int base4 = blk * (PH1_ITEMS / 4);
    #pragma unroll
    for (int k = 0; k < 4; ++k) {
        int i4 = base4 + k * 256 + t;
        if (i4 * 4 < N_INC) {
            int4 n4 = ((const int4*)ei0)[i4];
            int4 h4 = ((const int4*)ei1)[i4];
            int nn[4] = {n4.x, n4.y, n4.z, n4.w};
            int hhv[4] = {h4.x, h4.y, h4.z, h4.w};
            #pragma unroll
            for (int e = 0; e < 4; ++e) {
                int n = nn[e], h = hhv[e];
                int bn = n >> SHIFT, bh = h >> SHIFT;
                int rn = atomicAdd(&hn[bn], 1);
                int rh = atomicAdd(&hh[bh], 1);
                int pn = rown[bn] + boff_n[bn] + rn;
                int ph = rowh[bh] + boff_h[bh] + rh;
                payload_n[pn] = ((u32)(n & BMASK) << 17) | (u32)h;   // dest=node, src=hedge
                payload_h[ph] = ((u32)(h & BMASK) << 17) | (u32)n;   // dest=hedge, src=node
            }
        }
    }
}

// 2: wave-per-bucket: 128-bin LDS count + shuffle scan -> CSR off + sorted slots.
//    Wave w of block handles bucket bk = blockIdx.x*4 + w; bk in [0, 2*NBKT).
__global__ void phase2_kernel(const u32* __restrict__ payload_n, const u32* __restrict__ payload_h,
                              const int* __restrict__ boff_n, const int* __restrict__ boff_h,
                              int* __restrict__ off_n, int* __restrict__ off_h,
                              int* __restrict__ slot_n, int* __restrict__ slot_h) {
    __shared__ int hist[4][128];
    __shared__ int curs[4][128];
    int t = threadIdx.x;
    int w = t >> 6, lane = t & 63;
    int bk = blockIdx.x * 4 + w;
    int dir = (bk >= NBKT) ? 1 : 0;
    int b = bk - dir * NBKT;
    const u32* payload = dir ? payload_h : payload_n;
    const int* boff    = dir ? boff_h    : boff_n;
    int* off  = dir ? off_h  : off_n;
    int* slot = dir ? slot_h : slot_n;

    hist[w][lane] = 0; hist[w][64 + lane] = 0;
    int base = boff[b], end = boff[b + 1];
    // count (wave-private LDS region; intra-wave DS ordering)
    for (int j = base + lane; j < end; j += 64) atomicAdd(&hist[w][payload[j] >> 17], 1);
    __syncthreads();
    int h0 = hist[w][lane], h1 = hist[w][64 + lane];
    // wave-wide exclusive scan over 128 bins via shuffles
    int s0 = h0, s1 = h1;
    #pragma unroll
    for (int d = 1; d < 64; d <<= 1) {
        int u0 = __shfl_up(s0, d);
        int u1 = __shfl_up(s1, d);
        if (lane >= d) { s0 += u0; s1 += u1; }
    }
    int tot0 = __shfl(s0, 63);
    int e0 = s0 - h0;
    int e1 = tot0 + s1 - h1;
    int dest0 = (b << SHIFT) + lane;
    int dest1 = dest0 + 64;
    if (dest0 < N_NODES) off[dest0] = base + e0;
    if (dest1 < N_NODES) off[dest1] = base + e1;
    curs[w][lane] = e0; curs[w][64 + lane] = e1;
    __syncthreads();
    // scatter into dest-sorted order
    for (int j = base + lane; j < end; j += 64) {
        u32 p = payload[j];
        int r = atomicAdd(&curs[w][p >> 17], 1);
        slot[base + r] = (int)(p & 0x1FFFF);
    }
}

// ---------------------------------------------------------------------------
// dst[r] = (1/deg) * sum_{j in seg(r)} src[slot[j]]  (+ addv), rows = 4 floats
__global__ void gather_kernel(const float* __restrict__ src, float* __restrict__ dst,
                              const int* __restrict__ off, const int* __restrict__ slot,
                              const float* __restrict__ addv, int nrows) {
    int r = blockIdx.x * blockDim.x + threadIdx.x;
    if (r >= nrows) return;
    int s = off[r], e = off[r + 1];
    float a0 = 0.f, a1 = 0.f, a2 = 0.f;
    for (int j = s; j < e; ++j) {
        float4 v = ((const float4*)src)[slot[j]];
        a0 += v.x; a1 += v.y; a2 += v.z;
    }
    float inv = (e > s) ? 1.0f / (float)(e - s) : 0.f;
    float b0 = 0.f, b1 = 0.f, b2 = 0.f;
    if (addv) { b0 = addv[0]; b1 = addv[1]; b2 = addv[2]; }
    ((float4*)dst)[r] = make_float4(a0 * inv + b0, a1 * inv + b1, a2 * inv + b2, 0.f);
}

// per-hedge: gather-mean of H2 -> sigmoid -> rowsum-normalize -> +gumbel -> argmax
__global__ void hedge_final_kernel(const float* __restrict__ H2,
                                   const int* __restrict__ off_h, const int* __restrict__ slot_h,
                                   const float* __restrict__ gu, float* __restrict__ hard0,
                                   float* __restrict__ hard2, int n) {
    int h = blockIdx.x * blockDim.x + threadIdx.x;
    if (h >= n) return;
    int s = off_h[h], e = off_h[h + 1];
    float a0 = 0.f, a1 = 0.f, a2 = 0.f;
    for (int j = s; j < e; ++j) {
        float4 v = ((const float4*)H2)[slot_h[j]];
        a0 += v.x; a1 += v.y; a2 += v.z;
    }
    float binv = (e > s) ? 1.0f / (float)(e - s) : 0.f;
    float s0 = a0 * binv, s1 = a1 * binv, s2 = a2 * binv;
    float x0 = 1.0f / (1.0f + expf(-s0));
    float x1 = 1.0f / (1.0f + expf(-s1));
    float x2 = 1.0f / (1.0f + expf(-s2));
    float rs = x0 + x1 + x2;
    float rinv = rs != 0.f ? 1.0f / rs : 0.f;
    x0 *= rinv; x1 *= rinv; x2 *= rinv;
    const float EPS = 1e-10f;
    float g0 = -logf(-logf(gu[(size_t)h * 3 + 0] + EPS) + EPS);
    float g1 = -logf(-logf(gu[(size_t)h * 3 + 1] + EPS) + EPS);
    float g2 = -logf(-logf(gu[(size_t)h * 3 + 2] + EPS) + EPS);
    // argmax(softmax(x)) == argmax(x); first-max wins like jnp.argmax
    float v0 = x0 + g0, v1 = x1 + g1, v2 = x2 + g2;
    int am = 0; float vm = v0;
    if (v1 > vm) { am = 1; vm = v1; }
    if (v2 > vm) { am = 2; vm = v2; }
    hard0[h] = (am == 0) ? 1.f : 0.f;
    hard2[h] = (am == 2) ? 1.f : 0.f;
}

// per-incidence: sample + masked edge_index (int4 streams, float4 writes)
__global__ void edge_final_kernel(const float* __restrict__ hard0, const float* __restrict__ hard2,
                                  const float* __restrict__ ov,
                                  const int* __restrict__ ei0, const int* __restrict__ ei1,
                                  float* __restrict__ out, int n4) {
    int i4 = blockIdx.x * blockDim.x + threadIdx.x;
    if (i4 >= n4) return;
    int4 n4v = ((const int4*)ei0)[i4];
    int4 h4v = ((const int4*)ei1)[i4];
    int nn[4] = {n4v.x, n4v.y, n4v.z, n4v.w};
    int hh[4] = {h4v.x, h4v.y, h4v.z, h4v.w};
    float smp[4], oi[4], oh[4];
    #pragma unroll
    for (int e = 0; e < 4; ++e) {
        float r = hard0[hh[e]];
        float m = hard2[hh[e]] * (ov[nn[e]] < 0.5f ? 1.f : 0.f);
        float s = fmaxf(r, m);
        smp[e] = s;
        bool keep = s > 0.f;
        oi[e] = keep ? (float)nn[e] : -1.f;
        oh[e] = keep ? (float)hh[e] : -1.f;
    }
    ((float4*)out)[i4] = make_float4(smp[0], smp[1], smp[2], smp[3]);
    ((float4*)(out + N_INC))[i4] = make_float4(oi[0], oi[1], oi[2], oi[3]);
    ((float4*)(out + 2 * (size_t)N_INC))[i4] = make_float4(oh[0], oh[1], oh[2], oh[3]);
}

// ---------------------------------------------------------------------------
extern "C" void kernel_launch(void* const* d_in, const int* in_sizes, int n_in,
                              void* d_out, int out_size, void* d_ws, size_t ws_size,
                              hipStream_t stream) {
    const float* X  = (const float*)d_in[0];
    const float* W1 = (const float*)d_in[1];
    const float* b1 = (const float*)d_in[2];
    const float* W2 = (const float*)d_in[3];
    const float* b2 = (const float*)d_in[4];
    const float* ov = (const float*)d_in[5];
    const float* gu = (const float*)d_in[6];
    const int*   ei = (const int*)d_in[7];
    const int* ei0 = ei;            // nodes
    const int* ei1 = ei + N_INC;    // hedges

    // ---- workspace layout (no aliasing; all section starts 16B aligned) ----
    int* ip = (int*)d_ws;
    u32* payload_n = (u32*)ip;                    // 1M
    u32* payload_h = payload_n + N_INC;           // 1M
    int* slot_n    = (int*)(payload_h + N_INC);   // 1M
    int* slot_h    = slot_n + N_INC;              // 1M
    int* off_n     = slot_h + N_INC;              // 100004
    int* off_h     = off_n + 100004;              // 100004
    int* histmat   = off_h + 100004;              // 2*NBLK*NBKT = 383180 -> 383200
    int* tot       = histmat + 383200;            // 2*NBKT = 1564 -> 1568
    int* boff_n    = tot + 1568;                  // 784
    int* boff_h    = boff_n + 784;                // 784
    float* W12     = (float*)(boff_h + 784);      // 384
    float* cvec    = W12 + 384;                   // 4 (+12 pad)
    float* Z       = cvec + 12;                   // 4*N_NODES
    float* XeA     = Z    + 4 * N_NODES;          // 4*N_HEDGES
    float* XnA     = XeA  + 4 * N_HEDGES;         // 4*N_NODES
    float* XeB     = XnA  + 4 * N_NODES;          // 4*N_HEDGES
    float* XnB     = XeB  + 4 * N_HEDGES;         // 4*N_NODES (= H2)
    float* hard0   = XnB  + 4 * N_NODES;          // 100k
    float* hard2   = hard0 + N_HEDGES;            // 100k

    const int TB = 256;
    int gHed = (N_HEDGES + TB - 1) / TB;

    // CSR build front + fused W12
    bin_count_w12_kernel<<<NBLK, 256, 0, stream>>>(ei0, ei1, histmat, W1, b1, W2, W12, cvec);
    gemm_z_kernel<<<(N_NODES + 3) / 4, 256, 0, stream>>>(X, W12, Z, N_NODES);
    scanA_kernel<<<(2 * NBKT + 3) / 4, 256, 0, stream>>>(histmat, tot);
    scanB_kernel<<<1, 1024, 0, stream>>>(tot, boff_n, boff_h, off_n, off_h);
    place_kernel<<<NBLK, 256, 0, stream>>>(ei0, ei1, histmat, boff_n, boff_h,
                                           payload_n, payload_h);
    phase2_kernel<<<(2 * NBKT) / 4, 256, 0, stream>>>(payload_n, payload_h, boff_n, boff_h,
                                                      off_n, off_h, slot_n, slot_h);

    // layer 1: Xe = mean_hedge(Z); Xn = mean_node(Xe) + cvec
    gather_kernel<<<gHed, TB, 0, stream>>>(Z,   XeA, off_h, slot_h, nullptr, N_HEDGES);
    gather_kernel<<<gHed, TB, 0, stream>>>(XeA, XnA, off_n, slot_n, cvec,    N_NODES);
    // layer 2: H2 = mean_node(mean_hedge(XnA)) + b2
    gather_kernel<<<gHed, TB, 0, stream>>>(XnA, XeB, off_h, slot_h, nullptr, N_HEDGES);
    gather_kernel<<<gHed, TB, 0, stream>>>(XeB, XnB, off_n, slot_n, b2,      N_NODES);

    // scatter-mean of H2 into hedges fused with sigmoid/normalize/gumbel/argmax
    hedge_final_kernel<<<gHed, TB, 0, stream>>>(XnB, off_h, slot_h, gu, hard0, hard2, N_HEDGES);

    edge_final_kernel<<<(N_INC / 4 + TB - 1) / TB, TB, 0, stream>>>(hard0, hard2, ov, ei0, ei1,
                                                                    (float*)d_out, N_INC / 4);
}